// Round 1
// 209.070 us; speedup vs baseline: 1.0225x; 1.0225x over previous
//
#include <hip/hip_runtime.h>

// Input: x (32, 256, 64, 64) fp32. STRIDE=2, P=2. H,W even -> no padding.
//
// Pass 1 (aps_partials): pure lane-contiguous f4 stream (1 KiB dense per
// wave-load). Each lane's row parity (h&1) is FIXED across the grid-stride
// (+16384 f4 preserves (q>>4)&1), so each lane accumulates just two sums
// (sA = w-even, sB = w-odd); the parity-split shuffle tree sorts them into
// the 4 polyphase components at reduction time. Unroll x4 + lb(256,8) for
// 32 waves/CU of MLP.
//
// Pass 2 (aps_gather): redundant per-block argmax over the 64 partials
// (L2-hot, strict > == jnp.argmax first-max tie rule), then a gather that
// walks the SELECTED rows lane-contiguously: per load insn the wave covers
// 4x256B dense segments (vs the old 16B-stride-32 scatter); each lane
// extracts 2 floats and NT-stores a float2 at out-f2 index == m (stores are
// 512B contiguous per wave). NT keeps x resident in L2/L3.

#define B 32
#define C 256
#define H 64
#define W 64
#define H2 32
#define W2 32
#define NBLK 64                              // pass-1 blocks per batch
#define IN_F4_PER_BATCH (C * H * W / 4)      // 262144
#define T1 (NBLK * 256)                      // 16384 pass-1 threads per batch
#define ITER1 (IN_F4_PER_BATCH / T1)         // 16
#define SEL_F2_PER_BATCH (C * H2 * W2 / 2)   // 131072 out float2 per batch
#define GBLK 128                             // pass-2 blocks per batch
#define T2 (GBLK * 256)                      // 32768
#define ITER2 (SEL_F2_PER_BATCH / T2)        // 4

typedef float floatx2 __attribute__((ext_vector_type(2)));

__global__ __launch_bounds__(256, 8) void aps_partials(const float4* __restrict__ x,
                                                       float* __restrict__ ws) {
    const int b = blockIdx.y;
    const float4* xb = x + (size_t)b * IN_F4_PER_BATCH;
    const int q0 = blockIdx.x * 256 + threadIdx.x;   // f4 index, lane-contiguous
    float sA = 0.f, sB = 0.f;                        // w-even / w-odd sums
#pragma unroll 4
    for (int it = 0; it < ITER1; ++it) {
        float4 v = xb[q0 + it * T1];                 // (q>>4)&1 invariant per lane
        sA += v.x * v.x + v.z * v.z;
        sB += v.y * v.y + v.w * v.w;
    }
    // lane row-parity: lanes 0-15,32-47 -> h even; 16-31,48-63 -> h odd
    sA += __shfl_down(sA, 32);  sB += __shfl_down(sB, 32);
#pragma unroll
    for (int off = 8; off; off >>= 1) {
        sA += __shfl_down(sA, off);  sB += __shfl_down(sB, off);
    }
    // lane 0 holds (comp0, comp1) = (h even, w even/odd); lane 16 holds (comp2, comp3)
    __shared__ float sm[4][4];   // [wave][comp]
    const int lane = threadIdx.x & 63;
    const int wave = threadIdx.x >> 6;
    if (lane == 0)  { sm[wave][0] = sA; sm[wave][1] = sB; }
    if (lane == 16) { sm[wave][2] = sA; sm[wave][3] = sB; }
    __syncthreads();
    if (threadIdx.x < 4) {   // thread k writes comp k's partial
        const int k = threadIdx.x;
        float t = sm[0][k] + sm[1][k] + sm[2][k] + sm[3][k];
        // layout: ws[(b*4 + comp)*NBLK + bx]  -> contiguous per (b,comp)
        ws[(b * 4 + k) * NBLK + blockIdx.x] = t;
    }
}

__global__ __launch_bounds__(256, 8) void aps_gather(const float4* __restrict__ x,
                                                     const float* __restrict__ ws,
                                                     floatx2* __restrict__ out) {
    const int b = blockIdx.y;
    const int lane = threadIdx.x & 63;
    const int wave = threadIdx.x >> 6;   // 0..3 == component
    // redundant per-block reduction of this batch's 64 partials (L2-hot)
    float p = ws[(b * 4 + wave) * NBLK + lane];
    for (int off = 32; off; off >>= 1) p += __shfl_down(p, off);
    __shared__ float s4[4];
    if (lane == 0) s4[wave] = p;
    __syncthreads();
    const float v0 = s4[0], v1 = s4[1], v2 = s4[2], v3 = s4[3];
    float best = v0;
    int k = 0;
    if (v1 > best) { best = v1; k = 1; }
    if (v2 > best) { best = v2; k = 2; }
    if (v3 > best) { k = 3; }
    const int di = k >> 1;       // h offset of winning component
    const int dj = k & 1;        // w offset

    const float4* xb = x + (size_t)b * IN_F4_PER_BATCH;
    floatx2* ob = out + (size_t)b * SEL_F2_PER_BATCH;
    const int m0 = blockIdx.x * 256 + threadIdx.x;   // selected-f4 / out-f2 index
#pragma unroll
    for (int it = 0; it < ITER2; ++it) {
        const int m   = m0 + it * T2;
        const int ch  = m >> 9;          // 512 selected f4 per channel
        const int r   = (m >> 4) & 31;   // output row
        const int col = m & 15;          // f4 column within input row
        // lanes 0-15 share a row -> 4x256B dense segments per load insn
        float4 v = xb[(ch * 64 + 2 * r + di) * 16 + col];
        floatx2 o;
        if (dj == 0) { o.x = v.x; o.y = v.z; }   // w even
        else         { o.x = v.y; o.y = v.w; }   // w odd
        // out f2 index == m: wave stores are 512B contiguous; write-once -> NT
        __builtin_nontemporal_store(o, ob + m);
    }
}

extern "C" void kernel_launch(void* const* d_in, const int* in_sizes, int n_in,
                              void* d_out, int out_size, void* d_ws, size_t ws_size,
                              hipStream_t stream) {
    const float* x = (const float*)d_in[0];
    float* out = (float*)d_out;
    float* ws = (float*)d_ws;   // B*4*NBLK = 8192 floats of partials

    aps_partials<<<dim3(NBLK, B), 256, 0, stream>>>((const float4*)x, ws);
    aps_gather<<<dim3(GBLK, B), 256, 0, stream>>>((const float4*)x, ws, (floatx2*)out);
}